// Round 1
// baseline (177.516 us; speedup 1.0000x reference)
//
#include <hip/hip_runtime.h>
#include <cstddef>
#include <cstdint>

#define KTAGS 64
#define DDIM  512
#define TLEN  128
#define BSEQ  512
#define SEQ   126          // real word positions t = 1..126
#define BOS_T 63
#define EOS_T 62
#define NITEMS (BSEQ * SEQ)   // 64512

// ---------------------------------------------------------------------------
// Kernel 1: logemit[item][k] = dot(E[word_item], ThetaB[k])
// item = b*126 + (t-1), t in [1,126]
// Tiling: 32 words x 64 tags per block (256 threads), D chunked by 32.
// ---------------------------------------------------------------------------
#define WPB 32
#define DCH 32

__global__ __launch_bounds__(256) void emit_logits_kernel(
    const float* __restrict__ ThetaB, const float* __restrict__ E,
    const int* __restrict__ words, float* __restrict__ logemit)
{
    __shared__ float sE[WPB][DCH];          // 4 KB
    __shared__ float sTh[KTAGS][DCH + 4];   // 9 KB, +4 pad to break bank stride
    __shared__ int   sw[WPB];

    const int tx   = threadIdx.x;
    const int base = blockIdx.x * WPB;

    if (tx < WPB) {
        int item = base + tx;
        int b = item / SEQ;
        int r = item - b * SEQ;
        sw[tx] = words[b * TLEN + r + 1];
    }
    __syncthreads();

    const int kq = tx & 31;    // this thread's tag pair: {kq, kq+32}
    const int wq = tx >> 5;    // word group: words wq*4 .. wq*4+3

    float acc[4][2] = {{0.f,0.f},{0.f,0.f},{0.f,0.f},{0.f,0.f}};

    for (int c = 0; c < DDIM; c += DCH) {
        // stage E chunk: 32 words x 32 floats
        {
            int wi = tx >> 3;            // 0..31
            int d4 = (tx & 7) << 2;      // 0,4,..,28
            float4 v = *(const float4*)(E + (size_t)sw[wi] * DDIM + c + d4);
            *(float4*)&sE[wi][d4] = v;
        }
        // stage ThetaB chunk: 64 rows x 32 floats (coalesced)
        {
            int row = tx >> 3;           // 0..31
            int d4  = (tx & 7) << 2;
            float4 v0 = *(const float4*)(ThetaB + (size_t)row * DDIM + c + d4);
            float4 v1 = *(const float4*)(ThetaB + (size_t)(row + 32) * DDIM + c + d4);
            *(float4*)&sTh[row][d4]      = v0;
            *(float4*)&sTh[row + 32][d4] = v1;
        }
        __syncthreads();

        // register-cache this thread's two theta rows for the chunk
        float t0[DCH], t1[DCH];
        #pragma unroll
        for (int g = 0; g < DCH; g += 4) {
            *(float4*)&t0[g] = *(const float4*)&sTh[kq][g];
            *(float4*)&t1[g] = *(const float4*)&sTh[kq + 32][g];
        }

        #pragma unroll
        for (int wi = 0; wi < 4; ++wi) {
            const float* er = sE[wq * 4 + wi];
            #pragma unroll
            for (int g = 0; g < DCH; g += 4) {
                float4 ev = *(const float4*)&er[g];
                acc[wi][0] = fmaf(ev.x, t0[g],     acc[wi][0]);
                acc[wi][0] = fmaf(ev.y, t0[g + 1], acc[wi][0]);
                acc[wi][0] = fmaf(ev.z, t0[g + 2], acc[wi][0]);
                acc[wi][0] = fmaf(ev.w, t0[g + 3], acc[wi][0]);
                acc[wi][1] = fmaf(ev.x, t1[g],     acc[wi][1]);
                acc[wi][1] = fmaf(ev.y, t1[g + 1], acc[wi][1]);
                acc[wi][1] = fmaf(ev.z, t1[g + 2], acc[wi][1]);
                acc[wi][1] = fmaf(ev.w, t1[g + 3], acc[wi][1]);
            }
        }
        __syncthreads();
    }

    #pragma unroll
    for (int wi = 0; wi < 4; ++wi) {
        size_t item = (size_t)(base + wq * 4 + wi);
        logemit[item * KTAGS + kq]      = acc[wi][0];
        logemit[item * KTAGS + kq + 32] = acc[wi][1];
    }
}

// ---------------------------------------------------------------------------
// Kernel 2: per-sequence tagged log-prob (exact, log space) and unsupervised
// forward recursion (mirrors reference numerics). One 64-lane wave per seq.
// ---------------------------------------------------------------------------
__device__ __forceinline__ float bcast_lane(float v, int lane) {
    return __uint_as_float(__builtin_amdgcn_readlane(__float_as_uint(v), lane));
}

__global__ __launch_bounds__(64) void forward_kernel(
    const float* __restrict__ WA, const int* __restrict__ tags,
    const float* __restrict__ logemit, float* __restrict__ out)
{
    const int b    = blockIdx.x;
    const int lane = threadIdx.x;

    // Lane k caches column A[:,k] = exp(WA[:,k]); column BOS is forced 0.
    float Acol[KTAGS];
    #pragma unroll
    for (int j = 0; j < KTAGS; ++j) {
        float w = WA[j * KTAGS + lane];
        Acol[j] = (lane == BOS_T) ? 0.f : expf(w);
    }

    const int*   tr     = tags + b * TLEN;
    const float* lebase = logemit + (size_t)b * SEQ * KTAGS;

    // ---- tagged pass (exact in log space; rescaling telescopes away) ----
    float ts = 0.f;
    #pragma unroll
    for (int rep = 0; rep < 2; ++rep) {
        int t = 1 + lane + rep * 64;
        if (t <= SEQ) {
            int cur  = tr[t];
            int prev = (t == 1) ? BOS_T : tr[t - 1];
            ts += WA[prev * KTAGS + cur] + lebase[(size_t)(t - 1) * KTAGS + cur];
        }
    }
    #pragma unroll
    for (int off = 32; off > 0; off >>= 1) ts += __shfl_xor(ts, off);
    const float tagged = ts + WA[tr[SEQ] * KTAGS + EOS_T];

    // ---- unsupervised forward recursion ----
    float alpha  = (lane == BOS_T) ? 1.f : 0.f;
    float logsum = 0.f;

    float le_next = lebase[lane];   // prefetch t=0 row
    for (int t = 0; t < SEQ; ++t) {
        float le = le_next;
        if (t + 1 < SEQ) le_next = lebase[(size_t)(t + 1) * KTAGS + lane];

        float e = (lane >= EOS_T) ? 1e-45f : expf(le);

        float sc = alpha;
        #pragma unroll
        for (int off = 32; off > 0; off >>= 1) sc = fmaxf(sc, __shfl_xor(sc, off));

        float an = alpha * __builtin_amdgcn_rcpf(sc);

        float s0 = 0.f, s1 = 0.f, s2 = 0.f, s3 = 0.f;
        #pragma unroll
        for (int j = 0; j < KTAGS; j += 4) {
            s0 = fmaf(bcast_lane(an, j + 0), Acol[j + 0], s0);
            s1 = fmaf(bcast_lane(an, j + 1), Acol[j + 1], s1);
            s2 = fmaf(bcast_lane(an, j + 2), Acol[j + 2], s2);
            s3 = fmaf(bcast_lane(an, j + 3), Acol[j + 3], s3);
        }
        alpha = ((s0 + s1) + (s2 + s3)) * e;
        logsum += logf(sc);
    }

    float sc = alpha;
    #pragma unroll
    for (int off = 32; off > 0; off >>= 1) sc = fmaxf(sc, __shfl_xor(sc, off));
    float an = alpha * __builtin_amdgcn_rcpf(sc);

    float r0 = 0.f, r1 = 0.f, r2 = 0.f, r3 = 0.f;
    #pragma unroll
    for (int j = 0; j < KTAGS; j += 4) {
        r0 = fmaf(bcast_lane(an, j + 0), Acol[j + 0], r0);
        r1 = fmaf(bcast_lane(an, j + 1), Acol[j + 1], r1);
        r2 = fmaf(bcast_lane(an, j + 2), Acol[j + 2], r2);
        r3 = fmaf(bcast_lane(an, j + 3), Acol[j + 3], r3);
    }
    float r = ((r0 + r1) + (r2 + r3));
    float val = bcast_lane(r, EOS_T);   // dot with A[:, EOS]

    float unsup = logf(val) + logsum + logf(sc);

    if (lane == 0) out[b] = tagged - unsup;
}

// ---------------------------------------------------------------------------
extern "C" void kernel_launch(void* const* d_in, const int* in_sizes, int n_in,
                              void* d_out, int out_size, void* d_ws, size_t ws_size,
                              hipStream_t stream) {
    const float* WA     = (const float*)d_in[0];
    const float* ThetaB = (const float*)d_in[1];
    const float* E      = (const float*)d_in[2];
    const int*   words  = (const int*)d_in[3];
    const int*   tags   = (const int*)d_in[4];
    float*       out    = (float*)d_out;
    float*       logemit = (float*)d_ws;   // NITEMS * 64 floats = 15.75 MB

    emit_logits_kernel<<<dim3(NITEMS / WPB), dim3(256), 0, stream>>>(
        ThetaB, E, words, logemit);
    forward_kernel<<<dim3(BSEQ), dim3(64), 0, stream>>>(
        WA, tags, logemit, out);
}

// Round 2
// 92.743 us; speedup vs baseline: 1.9141x; 1.9141x over previous
//
#include <hip/hip_runtime.h>
#include <hip/hip_bf16.h>
#include <cstddef>
#include <cstdint>

#define KTAGS 64
#define DDIM  512
#define TLEN  128
#define BSEQ  512
#define SEQ   126          // real word positions t = 1..126
#define BOS_T 63
#define EOS_T 62
#define NITEMS (BSEQ * SEQ)   // 64512
#define NKS   (DDIM / 32)     // 16 K-steps of 32

typedef __attribute__((ext_vector_type(8))) short bf16x8;   // 8 bf16 = 4 VGPRs
typedef __attribute__((ext_vector_type(4))) float f32x4;
typedef __attribute__((ext_vector_type(4))) int   i32x4;

__device__ __forceinline__ short f2bf(float f) {
    uint32_t u = __float_as_uint(f);
    u += 0x7fffu + ((u >> 16) & 1u);       // RTNE (inputs are normal floats)
    return (short)(u >> 16);
}

// ---------------------------------------------------------------------------
// Kernel 0: pack ThetaB (f32 [64][512]) into bf16 MFMA B-frag order.
// idx = (ks*4+g)*64 + lane ; thp[idx*8+j] = bf16(Th[g*16+(lane&15)][ks*32+(lane>>4)*8+j])
// ---------------------------------------------------------------------------
__global__ __launch_bounds__(256) void pack_theta_kernel(
    const float* __restrict__ Th, short* __restrict__ thp)
{
    int idx  = blockIdx.x * 256 + threadIdx.x;   // 0..4095
    int lane = idx & 63;
    int gg   = (idx >> 6) & 3;
    int ks   = idx >> 8;
    int tag  = gg * 16 + (lane & 15);
    int kb   = ks * 32 + (lane >> 4) * 8;
    const float* src = Th + (size_t)tag * DDIM + kb;
    short tmp[8];
    #pragma unroll
    for (int j = 0; j < 8; ++j) tmp[j] = f2bf(src[j]);
    *(i32x4*)(thp + (size_t)idx * 8) = *(const i32x4*)tmp;
}

// ---------------------------------------------------------------------------
// Kernel 1: logemit[item][tag] = dot(E[word_item], ThetaB[tag]) via MFMA.
// Block = 256 threads = 4 waves; wave w computes items [blk*64+16w, +16) x 64 tags.
// ThetaB frags staged in LDS (64 KB, linear => conflict-free ds_read_b128).
// A-frags loaded from fp32 E rows (1-deep prefetch), converted to bf16.
// ---------------------------------------------------------------------------
__global__ __launch_bounds__(256) void emit_mfma_kernel(
    const float* __restrict__ E, const int* __restrict__ words,
    const short* __restrict__ thp, float* __restrict__ logemit)
{
    __shared__ short sth[NKS * 4 * 64 * 8];   // 64 KB

    const int tid = threadIdx.x;

    // stage packed theta -> LDS: 4096 x 16B, 16 iters of 256 threads
    #pragma unroll 4
    for (int it = 0; it < 16; ++it) {
        size_t off = (size_t)(it * 256 + tid) * 8;
        *(i32x4*)(sth + off) = *(const i32x4*)(thp + off);
    }

    const int wave = tid >> 6;
    const int lane = tid & 63;

    // my A-row: item index uses m = lane&15
    int item = blockIdx.x * 64 + wave * 16 + (lane & 15);
    int b = item / SEQ;
    int r = item - b * SEQ;
    int wid = words[b * TLEN + r + 1];
    const float* erow = E + (size_t)wid * DDIM + ((lane >> 4) * 8);

    __syncthreads();

    f32x4 acc0 = {0,0,0,0}, acc1 = {0,0,0,0}, acc2 = {0,0,0,0}, acc3 = {0,0,0,0};

    float4 a0 = *(const float4*)(erow);
    float4 a1 = *(const float4*)(erow + 4);

    for (int ks = 0; ks < NKS; ++ks) {
        // convert current A chunk to bf16 frag
        union { bf16x8 v; short h[8]; } cv;
        cv.h[0] = f2bf(a0.x); cv.h[1] = f2bf(a0.y);
        cv.h[2] = f2bf(a0.z); cv.h[3] = f2bf(a0.w);
        cv.h[4] = f2bf(a1.x); cv.h[5] = f2bf(a1.y);
        cv.h[6] = f2bf(a1.z); cv.h[7] = f2bf(a1.w);
        bf16x8 afrag = cv.v;

        // prefetch next A chunk
        if (ks + 1 < NKS) {
            a0 = *(const float4*)(erow + (ks + 1) * 32);
            a1 = *(const float4*)(erow + (ks + 1) * 32 + 4);
        }

        // B frags: linear, conflict-free
        const bf16x8* bbase = (const bf16x8*)sth + (ks * 4) * 64 + lane;
        bf16x8 b0 = bbase[0];
        bf16x8 b1 = bbase[64];
        bf16x8 b2 = bbase[128];
        bf16x8 b3 = bbase[192];

        acc0 = __builtin_amdgcn_mfma_f32_16x16x32_bf16(afrag, b0, acc0, 0, 0, 0);
        acc1 = __builtin_amdgcn_mfma_f32_16x16x32_bf16(afrag, b1, acc1, 0, 0, 0);
        acc2 = __builtin_amdgcn_mfma_f32_16x16x32_bf16(afrag, b2, acc2, 0, 0, 0);
        acc3 = __builtin_amdgcn_mfma_f32_16x16x32_bf16(afrag, b3, acc3, 0, 0, 0);
    }

    // epilogue: C layout col = lane&15, row = (lane>>4)*4 + rr
    const int col = lane & 15;
    const int m0  = (lane >> 4) * 4;
    #pragma unroll
    for (int rr = 0; rr < 4; ++rr) {
        size_t it2 = (size_t)(blockIdx.x * 64 + wave * 16 + m0 + rr);
        float* dst = logemit + it2 * KTAGS;
        dst[0 * 16 + col] = acc0[rr];
        dst[1 * 16 + col] = acc1[rr];
        dst[2 * 16 + col] = acc2[rr];
        dst[3 * 16 + col] = acc3[rr];
    }
}

// ---------------------------------------------------------------------------
// Kernel 2: tagged log-prob (exact, log space) + unsupervised forward.
// One 64-lane wave per sequence; rescale only every 8 steps.
// ---------------------------------------------------------------------------
__device__ __forceinline__ float bcast_lane(float v, int lane) {
    return __uint_as_float(__builtin_amdgcn_readlane(__float_as_uint(v), lane));
}

__global__ __launch_bounds__(64) void forward_kernel(
    const float* __restrict__ WA, const int* __restrict__ tags,
    const float* __restrict__ logemit, float* __restrict__ out)
{
    const int b    = blockIdx.x;
    const int lane = threadIdx.x;

    // Lane k caches column A[:,k] = exp(WA[:,k]); column BOS forced to 0.
    float Acol[KTAGS];
    #pragma unroll
    for (int j = 0; j < KTAGS; ++j) {
        float w = WA[j * KTAGS + lane];
        Acol[j] = (lane == BOS_T) ? 0.f : __expf(w);
    }

    const int*   tr     = tags + b * TLEN;
    const float* lebase = logemit + (size_t)b * SEQ * KTAGS;

    // ---- tagged pass ----
    float ts = 0.f;
    #pragma unroll
    for (int rep = 0; rep < 2; ++rep) {
        int t = 1 + lane + rep * 64;
        if (t <= SEQ) {
            int cur  = tr[t];
            int prev = (t == 1) ? BOS_T : tr[t - 1];
            ts += WA[prev * KTAGS + cur] + lebase[(size_t)(t - 1) * KTAGS + cur];
        }
    }
    #pragma unroll
    for (int off = 32; off > 0; off >>= 1) ts += __shfl_xor(ts, off);
    const float tagged = ts + WA[tr[SEQ] * KTAGS + EOS_T];

    // ---- unsupervised forward recursion ----
    float alpha  = (lane == BOS_T) ? 1.f : 0.f;
    float logsum = 0.f;

    float le_next = lebase[lane];
    for (int t = 0; t < SEQ; ++t) {
        float le = le_next;
        if (t + 1 < SEQ) le_next = lebase[(size_t)(t + 1) * KTAGS + lane];

        float e = (lane >= EOS_T) ? 1e-45f : __expf(le);

        float s0 = 0.f, s1 = 0.f, s2 = 0.f, s3 = 0.f;
        float s4 = 0.f, s5 = 0.f, s6 = 0.f, s7 = 0.f;
        #pragma unroll
        for (int j = 0; j < KTAGS; j += 8) {
            s0 = fmaf(bcast_lane(alpha, j + 0), Acol[j + 0], s0);
            s1 = fmaf(bcast_lane(alpha, j + 1), Acol[j + 1], s1);
            s2 = fmaf(bcast_lane(alpha, j + 2), Acol[j + 2], s2);
            s3 = fmaf(bcast_lane(alpha, j + 3), Acol[j + 3], s3);
            s4 = fmaf(bcast_lane(alpha, j + 4), Acol[j + 4], s4);
            s5 = fmaf(bcast_lane(alpha, j + 5), Acol[j + 5], s5);
            s6 = fmaf(bcast_lane(alpha, j + 6), Acol[j + 6], s6);
            s7 = fmaf(bcast_lane(alpha, j + 7), Acol[j + 7], s7);
        }
        float sum = ((s0 + s1) + (s2 + s3)) + ((s4 + s5) + (s6 + s7));
        alpha = sum * e;

        if ((t & 7) == 7) {   // rescale every 8 steps (growth <= ~112^8 ~ 2.5e16)
            float sc = alpha;
            #pragma unroll
            for (int off = 32; off > 0; off >>= 1) sc = fmaxf(sc, __shfl_xor(sc, off));
            alpha *= __builtin_amdgcn_rcpf(sc);
            logsum += logf(sc);
        }
    }

    // final transition into EOS (no rescale needed: alpha <= ~1e14)
    float r0 = 0.f, r1 = 0.f, r2 = 0.f, r3 = 0.f;
    #pragma unroll
    for (int j = 0; j < KTAGS; j += 4) {
        r0 = fmaf(bcast_lane(alpha, j + 0), Acol[j + 0], r0);
        r1 = fmaf(bcast_lane(alpha, j + 1), Acol[j + 1], r1);
        r2 = fmaf(bcast_lane(alpha, j + 2), Acol[j + 2], r2);
        r3 = fmaf(bcast_lane(alpha, j + 3), Acol[j + 3], r3);
    }
    float r = ((r0 + r1) + (r2 + r3));
    float val = bcast_lane(r, EOS_T);

    float unsup = logf(val) + logsum;

    if (lane == 0) out[b] = tagged - unsup;
}

// ---------------------------------------------------------------------------
extern "C" void kernel_launch(void* const* d_in, const int* in_sizes, int n_in,
                              void* d_out, int out_size, void* d_ws, size_t ws_size,
                              hipStream_t stream) {
    const float* WA     = (const float*)d_in[0];
    const float* ThetaB = (const float*)d_in[1];
    const float* E      = (const float*)d_in[2];
    const int*   words  = (const int*)d_in[3];
    const int*   tags   = (const int*)d_in[4];
    float*       out    = (float*)d_out;

    float* logemit = (float*)d_ws;                         // 16,515,072 B
    short* thp     = (short*)((char*)d_ws + 16515072);     // 65,536 B

    pack_theta_kernel<<<dim3(16), dim3(256), 0, stream>>>(ThetaB, thp);
    emit_mfma_kernel<<<dim3(NITEMS / 64), dim3(256), 0, stream>>>(
        E, words, thp, logemit);
    forward_kernel<<<dim3(BSEQ), dim3(64), 0, stream>>>(
        WA, tags, logemit, out);
}

// Round 3
// 85.266 us; speedup vs baseline: 2.0819x; 1.0877x over previous
//
#include <hip/hip_runtime.h>
#include <hip/hip_bf16.h>
#include <cstddef>
#include <cstdint>

#define KTAGS 64
#define DDIM  512
#define TLEN  128
#define BSEQ  512
#define SEQ   126          // real word positions t = 1..126
#define BOS_T 63
#define EOS_T 62
#define NITEMS (BSEQ * SEQ)   // 64512
#define NKS   (DDIM / 32)     // 16 K-steps of 32

typedef __attribute__((ext_vector_type(8))) short bf16x8;   // 8 bf16 = 4 VGPRs
typedef __attribute__((ext_vector_type(4))) float f32x4;
typedef __attribute__((ext_vector_type(4))) int   i32x4;

__device__ __forceinline__ short f2bf(float f) {
    uint32_t u = __float_as_uint(f);
    u += 0x7fffu + ((u >> 16) & 1u);       // RTNE (inputs are normal floats)
    return (short)(u >> 16);
}

// ---------------------------------------------------------------------------
// Kernel 0: pack ThetaB (f32 [64][512]) into bf16 MFMA B-frag order.
// ---------------------------------------------------------------------------
__global__ __launch_bounds__(256) void pack_theta_kernel(
    const float* __restrict__ Th, short* __restrict__ thp)
{
    int idx  = blockIdx.x * 256 + threadIdx.x;   // 0..4095
    int lane = idx & 63;
    int gg   = (idx >> 6) & 3;
    int ks   = idx >> 8;
    int tag  = gg * 16 + (lane & 15);
    int kb   = ks * 32 + (lane >> 4) * 8;
    const float* src = Th + (size_t)tag * DDIM + kb;
    short tmp[8];
    #pragma unroll
    for (int j = 0; j < 8; ++j) tmp[j] = f2bf(src[j]);
    *(i32x4*)(thp + (size_t)idx * 8) = *(const i32x4*)tmp;
}

// ---------------------------------------------------------------------------
// Kernel 1: logemit[item][tag] = dot(E[word_item], ThetaB[tag]) via MFMA.
// ---------------------------------------------------------------------------
__global__ __launch_bounds__(256) void emit_mfma_kernel(
    const float* __restrict__ E, const int* __restrict__ words,
    const short* __restrict__ thp, float* __restrict__ logemit)
{
    __shared__ short sth[NKS * 4 * 64 * 8];   // 64 KB

    const int tid = threadIdx.x;

    #pragma unroll 4
    for (int it = 0; it < 16; ++it) {
        size_t off = (size_t)(it * 256 + tid) * 8;
        *(i32x4*)(sth + off) = *(const i32x4*)(thp + off);
    }

    const int wave = tid >> 6;
    const int lane = tid & 63;

    int item = blockIdx.x * 64 + wave * 16 + (lane & 15);
    int b = item / SEQ;
    int r = item - b * SEQ;
    int wid = words[b * TLEN + r + 1];
    const float* erow = E + (size_t)wid * DDIM + ((lane >> 4) * 8);

    __syncthreads();

    f32x4 acc0 = {0,0,0,0}, acc1 = {0,0,0,0}, acc2 = {0,0,0,0}, acc3 = {0,0,0,0};

    float4 a0 = *(const float4*)(erow);
    float4 a1 = *(const float4*)(erow + 4);

    for (int ks = 0; ks < NKS; ++ks) {
        union { bf16x8 v; short h[8]; } cv;
        cv.h[0] = f2bf(a0.x); cv.h[1] = f2bf(a0.y);
        cv.h[2] = f2bf(a0.z); cv.h[3] = f2bf(a0.w);
        cv.h[4] = f2bf(a1.x); cv.h[5] = f2bf(a1.y);
        cv.h[6] = f2bf(a1.z); cv.h[7] = f2bf(a1.w);
        bf16x8 afrag = cv.v;

        if (ks + 1 < NKS) {
            a0 = *(const float4*)(erow + (ks + 1) * 32);
            a1 = *(const float4*)(erow + (ks + 1) * 32 + 4);
        }

        const bf16x8* bbase = (const bf16x8*)sth + (ks * 4) * 64 + lane;
        bf16x8 b0 = bbase[0];
        bf16x8 b1 = bbase[64];
        bf16x8 b2 = bbase[128];
        bf16x8 b3 = bbase[192];

        acc0 = __builtin_amdgcn_mfma_f32_16x16x32_bf16(afrag, b0, acc0, 0, 0, 0);
        acc1 = __builtin_amdgcn_mfma_f32_16x16x32_bf16(afrag, b1, acc1, 0, 0, 0);
        acc2 = __builtin_amdgcn_mfma_f32_16x16x32_bf16(afrag, b2, acc2, 0, 0, 0);
        acc3 = __builtin_amdgcn_mfma_f32_16x16x32_bf16(afrag, b3, acc3, 0, 0, 0);
    }

    const int col = lane & 15;
    const int m0  = (lane >> 4) * 4;
    #pragma unroll
    for (int rr = 0; rr < 4; ++rr) {
        size_t it2 = (size_t)(blockIdx.x * 64 + wave * 16 + m0 + rr);
        float* dst = logemit + it2 * KTAGS;
        dst[0 * 16 + col] = acc0[rr];
        dst[1 * 16 + col] = acc1[rr];
        dst[2 * 16 + col] = acc2[rr];
        dst[3 * 16 + col] = acc3[rr];
    }
}

// ---------------------------------------------------------------------------
// Kernel 2: tagged log-prob + unsupervised forward; 4-deep emission prefetch.
// ---------------------------------------------------------------------------
__device__ __forceinline__ float bcast_lane(float v, int lane) {
    return __uint_as_float(__builtin_amdgcn_readlane(__float_as_uint(v), lane));
}

__global__ __launch_bounds__(64) void forward_kernel(
    const float* __restrict__ WA, const int* __restrict__ tags,
    const float* __restrict__ logemit, float* __restrict__ out)
{
    const int b    = blockIdx.x;
    const int lane = threadIdx.x;

    // Lane k caches column A[:,k] = exp(WA[:,k]); column BOS forced to 0.
    float Acol[KTAGS];
    #pragma unroll
    for (int j = 0; j < KTAGS; ++j) {
        float w = WA[j * KTAGS + lane];
        Acol[j] = (lane == BOS_T) ? 0.f : __expf(w);
    }

    const int*   tr     = tags + b * TLEN;
    const float* lebase = logemit + (size_t)b * SEQ * KTAGS;

    // ---- tagged pass ----
    float ts = 0.f;
    #pragma unroll
    for (int rep = 0; rep < 2; ++rep) {
        int t = 1 + lane + rep * 64;
        if (t <= SEQ) {
            int cur  = tr[t];
            int prev = (t == 1) ? BOS_T : tr[t - 1];
            ts += WA[prev * KTAGS + cur] + lebase[(size_t)(t - 1) * KTAGS + cur];
        }
    }
    #pragma unroll
    for (int off = 32; off > 0; off >>= 1) ts += __shfl_xor(ts, off);
    const float tagged = ts + WA[tr[SEQ] * KTAGS + EOS_T];

    // ---- unsupervised forward recursion ----
    float alpha  = (lane == BOS_T) ? 1.f : 0.f;
    float logsum = 0.f;

#define LE(idx) lebase[(size_t)(idx) * KTAGS + lane]
#define STEP(le_reg)                                                        \
    {                                                                       \
        float e = (lane >= EOS_T) ? 1e-45f : __expf(le_reg);                \
        float s0 = 0.f, s1 = 0.f, s2 = 0.f, s3 = 0.f;                       \
        float s4 = 0.f, s5 = 0.f, s6 = 0.f, s7 = 0.f;                       \
        _Pragma("unroll")                                                   \
        for (int j = 0; j < KTAGS; j += 8) {                                \
            s0 = fmaf(bcast_lane(alpha, j + 0), Acol[j + 0], s0);           \
            s1 = fmaf(bcast_lane(alpha, j + 1), Acol[j + 1], s1);           \
            s2 = fmaf(bcast_lane(alpha, j + 2), Acol[j + 2], s2);           \
            s3 = fmaf(bcast_lane(alpha, j + 3), Acol[j + 3], s3);           \
            s4 = fmaf(bcast_lane(alpha, j + 4), Acol[j + 4], s4);           \
            s5 = fmaf(bcast_lane(alpha, j + 5), Acol[j + 5], s5);           \
            s6 = fmaf(bcast_lane(alpha, j + 6), Acol[j + 6], s6);           \
            s7 = fmaf(bcast_lane(alpha, j + 7), Acol[j + 7], s7);           \
        }                                                                   \
        alpha = (((s0 + s1) + (s2 + s3)) + ((s4 + s5) + (s6 + s7))) * e;    \
    }
#define RESCALE                                                             \
    {                                                                       \
        float sc = alpha;                                                   \
        _Pragma("unroll")                                                   \
        for (int off = 32; off > 0; off >>= 1)                              \
            sc = fmaxf(sc, __shfl_xor(sc, off));                            \
        alpha *= __builtin_amdgcn_rcpf(sc);                                 \
        logsum += logf(sc);                                                 \
    }

    // 4-deep prefetch ring, statically indexed (unroll-by-4 main loop).
    float r0 = LE(0), r1 = LE(1), r2 = LE(2), r3 = LE(3);

    int t = 0;
    for (; t + 4 <= SEQ - 2; t += 4) {       // main loop: steps 0..123
        int p = t + 4;
        STEP(r0); r0 = LE(p < SEQ ? p : SEQ - 1);
        STEP(r1); r1 = LE(p + 1 < SEQ ? p + 1 : SEQ - 1);
        STEP(r2); r2 = LE(p + 2 < SEQ ? p + 2 : SEQ - 1);
        STEP(r3); r3 = LE(p + 3 < SEQ ? p + 3 : SEQ - 1);
        if (t & 4) RESCALE;                  // after step t+3 with (t+3)%8==7
    }
    // tail: steps 124, 125 (last rescale was after step 119)
    STEP(r0);
    STEP(r1);

    // final transition into EOS (growth since step 119 <= ~123^7 ~ 4e14: safe)
    float q0 = 0.f, q1 = 0.f, q2 = 0.f, q3 = 0.f;
    #pragma unroll
    for (int j = 0; j < KTAGS; j += 4) {
        q0 = fmaf(bcast_lane(alpha, j + 0), Acol[j + 0], q0);
        q1 = fmaf(bcast_lane(alpha, j + 1), Acol[j + 1], q1);
        q2 = fmaf(bcast_lane(alpha, j + 2), Acol[j + 2], q2);
        q3 = fmaf(bcast_lane(alpha, j + 3), Acol[j + 3], q3);
    }
    float rr  = ((q0 + q1) + (q2 + q3));
    float val = bcast_lane(rr, EOS_T);

    float unsup = logf(val) + logsum;

    if (lane == 0) out[b] = tagged - unsup;
#undef LE
#undef STEP
#undef RESCALE
}

// ---------------------------------------------------------------------------
extern "C" void kernel_launch(void* const* d_in, const int* in_sizes, int n_in,
                              void* d_out, int out_size, void* d_ws, size_t ws_size,
                              hipStream_t stream) {
    const float* WA     = (const float*)d_in[0];
    const float* ThetaB = (const float*)d_in[1];
    const float* E      = (const float*)d_in[2];
    const int*   words  = (const int*)d_in[3];
    const int*   tags   = (const int*)d_in[4];
    float*       out    = (float*)d_out;

    float* logemit = (float*)d_ws;                         // 16,515,072 B
    short* thp     = (short*)((char*)d_ws + 16515072);     // 65,536 B

    pack_theta_kernel<<<dim3(16), dim3(256), 0, stream>>>(ThetaB, thp);
    emit_mfma_kernel<<<dim3(NITEMS / 64), dim3(256), 0, stream>>>(
        E, words, thp, logemit);
    forward_kernel<<<dim3(BSEQ), dim3(64), 0, stream>>>(
        WA, tags, logemit, out);
}

// Round 4
// 83.163 us; speedup vs baseline: 2.1346x; 1.0253x over previous
//
#include <hip/hip_runtime.h>
#include <hip/hip_bf16.h>
#include <cstddef>
#include <cstdint>

#define KTAGS 64
#define DDIM  512
#define TLEN  128
#define BSEQ  512
#define SEQ   126          // real word positions t = 1..126
#define BOS_T 63
#define EOS_T 62
#define NKS   (DDIM / 32)  // 16 K-steps of 32

typedef __attribute__((ext_vector_type(8))) short bf16x8;   // 8 bf16 = 4 VGPRs
typedef __attribute__((ext_vector_type(4))) float f32x4;
typedef __attribute__((ext_vector_type(4))) int   i32x4;

__device__ __forceinline__ short f2bf(float f) {
    uint32_t u = __float_as_uint(f);
    u += 0x7fffu + ((u >> 16) & 1u);       // RTNE
    return (short)(u >> 16);
}

__device__ __forceinline__ float bcast_lane(float v, int lane) {
    return __uint_as_float(__builtin_amdgcn_readlane(__float_as_uint(v), lane));
}

// ---------------------------------------------------------------------------
// Kernel 0: pack ThetaB (f32 [64][512]) into bf16 MFMA B-frag order.
// frag idx = (ks*4+g)*64 + lane ; holds Th[g*16+(lane&15)][ks*32+(lane>>4)*8 +j]
// ---------------------------------------------------------------------------
__global__ __launch_bounds__(256) void pack_theta_kernel(
    const float* __restrict__ Th, short* __restrict__ thp)
{
    int idx  = blockIdx.x * 256 + threadIdx.x;   // 0..4095
    int lane = idx & 63;
    int gg   = (idx >> 6) & 3;
    int ks   = idx >> 8;
    int tag  = gg * 16 + (lane & 15);
    int kb   = ks * 32 + (lane >> 4) * 8;
    const float* src = Th + (size_t)tag * DDIM + kb;
    short tmp[8];
    #pragma unroll
    for (int j = 0; j < 8; ++j) tmp[j] = f2bf(src[j]);
    *(i32x4*)(thp + (size_t)idx * 8) = *(const i32x4*)tmp;
}

// ---------------------------------------------------------------------------
// Fused kernel: one block (4 waves) per sequence.
//   phase 1 (all waves): MFMA emissions for this sequence -> exp -> LDS
//   phase 2 (wave 0):    tagged log-prob + 126-step forward recursion
// ---------------------------------------------------------------------------
__global__ __launch_bounds__(256, 4) void fused_kernel(
    const float* __restrict__ WA, const float* __restrict__ E,
    const int* __restrict__ words, const int* __restrict__ tags,
    const short* __restrict__ thp, float* __restrict__ out)
{
    __shared__ float e_lds[128][KTAGS];   // 32 KB: e[t][tag], rows 126,127 pad

    const int b    = blockIdx.x;
    const int tid  = threadIdx.x;
    const int wave = tid >> 6;
    const int lane = tid & 63;

    // ---- emit phase: wave handles item-tiles {wave, wave+4} ----
    #pragma unroll
    for (int tt = 0; tt < 2; ++tt) {
        const int tile = wave + tt * 4;
        int item = tile * 16 + (lane & 15);
        int it   = item < SEQ ? item : SEQ - 1;       // clamp pad rows
        int wid  = words[b * TLEN + it + 1];
        const float* erow = E + (size_t)wid * DDIM + ((lane >> 4) * 8);

        f32x4 acc0 = {0,0,0,0}, acc1 = {0,0,0,0}, acc2 = {0,0,0,0}, acc3 = {0,0,0,0};

        float4 a0 = *(const float4*)(erow);
        float4 a1 = *(const float4*)(erow + 4);

        for (int ks = 0; ks < NKS; ++ks) {
            union { bf16x8 v; short h[8]; } cv;
            cv.h[0] = f2bf(a0.x); cv.h[1] = f2bf(a0.y);
            cv.h[2] = f2bf(a0.z); cv.h[3] = f2bf(a0.w);
            cv.h[4] = f2bf(a1.x); cv.h[5] = f2bf(a1.y);
            cv.h[6] = f2bf(a1.z); cv.h[7] = f2bf(a1.w);
            bf16x8 afrag = cv.v;

            if (ks + 1 < NKS) {
                a0 = *(const float4*)(erow + (ks + 1) * 32);
                a1 = *(const float4*)(erow + (ks + 1) * 32 + 4);
            }

            const bf16x8* bbase = (const bf16x8*)thp + (ks * 4) * 64 + lane;
            bf16x8 b0 = bbase[0];
            bf16x8 b1 = bbase[64];
            bf16x8 b2 = bbase[128];
            bf16x8 b3 = bbase[192];

            acc0 = __builtin_amdgcn_mfma_f32_16x16x32_bf16(afrag, b0, acc0, 0, 0, 0);
            acc1 = __builtin_amdgcn_mfma_f32_16x16x32_bf16(afrag, b1, acc1, 0, 0, 0);
            acc2 = __builtin_amdgcn_mfma_f32_16x16x32_bf16(afrag, b2, acc2, 0, 0, 0);
            acc3 = __builtin_amdgcn_mfma_f32_16x16x32_bf16(afrag, b3, acc3, 0, 0, 0);
        }

        // epilogue: e = exp(logit); tags 62(EOS)/63(BOS) forced to 1e-45
        const int col = lane & 15;
        const int m0  = tile * 16 + (lane >> 4) * 4;
        #pragma unroll
        for (int rr = 0; rr < 4; ++rr) {
            e_lds[m0 + rr][0 * 16 + col] = __expf(acc0[rr]);
            e_lds[m0 + rr][1 * 16 + col] = __expf(acc1[rr]);
            e_lds[m0 + rr][2 * 16 + col] = __expf(acc2[rr]);
            float v3 = __expf(acc3[rr]);
            if (48 + col >= EOS_T) v3 = 1e-45f;
            e_lds[m0 + rr][3 * 16 + col] = v3;
        }
    }

    __syncthreads();
    if (wave != 0) return;

    // ---- wave 0 only ----
    // Lane k caches column A[:,k] = exp(WA[:,k]); column BOS forced to 0.
    float Acol[KTAGS];
    #pragma unroll
    for (int j = 0; j < KTAGS; ++j) {
        float w = WA[j * KTAGS + lane];
        Acol[j] = (lane == BOS_T) ? 0.f : __expf(w);
    }

    const int* tr = tags + b * TLEN;

    // tagged pass (exact in log space)
    float ts = 0.f;
    #pragma unroll
    for (int rep = 0; rep < 2; ++rep) {
        int t = 1 + lane + rep * 64;
        if (t <= SEQ) {
            int cur  = tr[t];
            int prev = (t == 1) ? BOS_T : tr[t - 1];
            ts += WA[prev * KTAGS + cur] + __logf(e_lds[t - 1][cur]);
        }
    }
    #pragma unroll
    for (int off = 32; off > 0; off >>= 1) ts += __shfl_xor(ts, off);
    const float tagged = ts + WA[tr[SEQ] * KTAGS + EOS_T];

    // unsupervised forward recursion
    float alpha  = (lane == BOS_T) ? 1.f : 0.f;
    float logsum = 0.f;

#define STEP(e_reg)                                                         \
    {                                                                       \
        float s0 = 0.f, s1 = 0.f, s2 = 0.f, s3 = 0.f;                       \
        float s4 = 0.f, s5 = 0.f, s6 = 0.f, s7 = 0.f;                       \
        _Pragma("unroll")                                                   \
        for (int j = 0; j < KTAGS; j += 8) {                                \
            s0 = fmaf(bcast_lane(alpha, j + 0), Acol[j + 0], s0);           \
            s1 = fmaf(bcast_lane(alpha, j + 1), Acol[j + 1], s1);           \
            s2 = fmaf(bcast_lane(alpha, j + 2), Acol[j + 2], s2);           \
            s3 = fmaf(bcast_lane(alpha, j + 3), Acol[j + 3], s3);           \
            s4 = fmaf(bcast_lane(alpha, j + 4), Acol[j + 4], s4);           \
            s5 = fmaf(bcast_lane(alpha, j + 5), Acol[j + 5], s5);           \
            s6 = fmaf(bcast_lane(alpha, j + 6), Acol[j + 6], s6);           \
            s7 = fmaf(bcast_lane(alpha, j + 7), Acol[j + 7], s7);           \
        }                                                                   \
        alpha = (((s0 + s1) + (s2 + s3)) + ((s4 + s5) + (s6 + s7))) * (e_reg); \
    }
#define RESCALE                                                             \
    {                                                                       \
        float sc = alpha;                                                   \
        _Pragma("unroll")                                                   \
        for (int off = 32; off > 0; off >>= 1)                              \
            sc = fmaxf(sc, __shfl_xor(sc, off));                            \
        alpha *= __builtin_amdgcn_rcpf(sc);                                 \
        logsum += logf(sc);                                                 \
    }

    float r0 = e_lds[0][lane];
    float r1 = e_lds[1][lane];

    int t = 0;
    for (; t + 2 <= SEQ - 2; t += 2) {       // steps 0..123
        STEP(r0); r0 = e_lds[t + 2][lane];
        STEP(r1); r1 = e_lds[(t + 3 < SEQ) ? t + 3 : SEQ - 1][lane];
        if ((t & 7) == 6) RESCALE;           // after steps 7,15,...,119
    }
    STEP(r0);                                // step 124
    STEP(r1);                                // step 125

    // final transition into EOS (growth since step 119 bounded ~5e15: safe)
    float q0 = 0.f, q1 = 0.f, q2 = 0.f, q3 = 0.f;
    #pragma unroll
    for (int j = 0; j < KTAGS; j += 4) {
        q0 = fmaf(bcast_lane(alpha, j + 0), Acol[j + 0], q0);
        q1 = fmaf(bcast_lane(alpha, j + 1), Acol[j + 1], q1);
        q2 = fmaf(bcast_lane(alpha, j + 2), Acol[j + 2], q2);
        q3 = fmaf(bcast_lane(alpha, j + 3), Acol[j + 3], q3);
    }
    float rr  = ((q0 + q1) + (q2 + q3));
    float val = bcast_lane(rr, EOS_T);

    float unsup = logf(val) + logsum;

    if (lane == 0) out[b] = tagged - unsup;
#undef STEP
#undef RESCALE
}

// ---------------------------------------------------------------------------
extern "C" void kernel_launch(void* const* d_in, const int* in_sizes, int n_in,
                              void* d_out, int out_size, void* d_ws, size_t ws_size,
                              hipStream_t stream) {
    const float* WA     = (const float*)d_in[0];
    const float* ThetaB = (const float*)d_in[1];
    const float* E      = (const float*)d_in[2];
    const int*   words  = (const int*)d_in[3];
    const int*   tags   = (const int*)d_in[4];
    float*       out    = (float*)d_out;

    short* thp = (short*)d_ws;   // 65,536 B packed bf16 ThetaB frags

    pack_theta_kernel<<<dim3(16), dim3(256), 0, stream>>>(ThetaB, thp);
    fused_kernel<<<dim3(BSEQ), dim3(256), 0, stream>>>(
        WA, E, words, tags, thp, out);
}

// Round 5
// 71.868 us; speedup vs baseline: 2.4700x; 1.1572x over previous
//
#include <hip/hip_runtime.h>
#include <hip/hip_bf16.h>
#include <cstddef>
#include <cstdint>

#define KTAGS 64
#define DDIM  512
#define TLEN  128
#define BSEQ  512
#define SEQ   126          // real word positions t = 1..126
#define BOS_T 63
#define EOS_T 62
#define NITEMS (BSEQ * SEQ)   // 64512
#define NKS   (DDIM / 32)     // 16 K-steps of 32

typedef __attribute__((ext_vector_type(8))) short bf16x8;   // 8 bf16 = 4 VGPRs
typedef __attribute__((ext_vector_type(4))) float f32x4;
typedef __attribute__((ext_vector_type(4))) int   i32x4;

__device__ __forceinline__ short f2bf(float f) {
    uint32_t u = __float_as_uint(f);
    u += 0x7fffu + ((u >> 16) & 1u);       // RTNE
    return (short)(u >> 16);
}

// ---------------------------------------------------------------------------
// Kernel 0: pack ThetaB (f32 [64][512]) into bf16 MFMA B-frag order.
// frag idx = (ks*4+g)*64 + lane ; holds Th[g*16+(lane&15)][ks*32+(lane>>4)*8+j]
// ---------------------------------------------------------------------------
__global__ __launch_bounds__(256) void pack_theta_kernel(
    const float* __restrict__ Th, short* __restrict__ thp)
{
    int idx  = blockIdx.x * 256 + threadIdx.x;   // 0..4095
    int lane = idx & 63;
    int gg   = (idx >> 6) & 3;
    int ks   = idx >> 8;
    int tag  = gg * 16 + (lane & 15);
    int kb   = ks * 32 + (lane >> 4) * 8;
    const float* src = Th + (size_t)tag * DDIM + kb;
    short tmp[8];
    #pragma unroll
    for (int j = 0; j < 8; ++j) tmp[j] = f2bf(src[j]);
    *(i32x4*)(thp + (size_t)idx * 8) = *(const i32x4*)tmp;
}

// ---------------------------------------------------------------------------
// Kernel 1: e[t][s][tag] = exp(dot(E[words[s][t+1]], ThetaB[tag])) via MFMA.
// Tags 62,63 forced to 1e-45. Output row = t*512 + s (coalesced for forward).
// No LDS: B-frags read straight from L2-resident packed theta.
// ---------------------------------------------------------------------------
__global__ __launch_bounds__(256) void emit_kernel(
    const float* __restrict__ E, const int* __restrict__ words,
    const short* __restrict__ thp, float* __restrict__ eout)
{
    const int tid  = threadIdx.x;
    const int wave = tid >> 6;
    const int lane = tid & 63;

    int item = blockIdx.x * 64 + wave * 16 + (lane & 15);
    int s = item / SEQ;
    int t = item - s * SEQ;
    int wid = words[s * TLEN + t + 1];
    const float* erow = E + (size_t)wid * DDIM + ((lane >> 4) * 8);

    f32x4 acc0 = {0,0,0,0}, acc1 = {0,0,0,0}, acc2 = {0,0,0,0}, acc3 = {0,0,0,0};

    float4 a0 = *(const float4*)(erow);
    float4 a1 = *(const float4*)(erow + 4);

    for (int ks = 0; ks < NKS; ++ks) {
        union { bf16x8 v; short h[8]; } cv;
        cv.h[0] = f2bf(a0.x); cv.h[1] = f2bf(a0.y);
        cv.h[2] = f2bf(a0.z); cv.h[3] = f2bf(a0.w);
        cv.h[4] = f2bf(a1.x); cv.h[5] = f2bf(a1.y);
        cv.h[6] = f2bf(a1.z); cv.h[7] = f2bf(a1.w);
        bf16x8 afrag = cv.v;

        if (ks + 1 < NKS) {
            a0 = *(const float4*)(erow + (ks + 1) * 32);
            a1 = *(const float4*)(erow + (ks + 1) * 32 + 4);
        }

        const bf16x8* bbase = (const bf16x8*)thp + (ks * 4) * 64 + lane;
        bf16x8 b0 = bbase[0];
        bf16x8 b1 = bbase[64];
        bf16x8 b2 = bbase[128];
        bf16x8 b3 = bbase[192];

        acc0 = __builtin_amdgcn_mfma_f32_16x16x32_bf16(afrag, b0, acc0, 0, 0, 0);
        acc1 = __builtin_amdgcn_mfma_f32_16x16x32_bf16(afrag, b1, acc1, 0, 0, 0);
        acc2 = __builtin_amdgcn_mfma_f32_16x16x32_bf16(afrag, b2, acc2, 0, 0, 0);
        acc3 = __builtin_amdgcn_mfma_f32_16x16x32_bf16(afrag, b3, acc3, 0, 0, 0);
    }

    // epilogue: C col = lane&15 (tag within block), row = (lane>>4)*4+rr (item)
    const int col = lane & 15;
    const int m0  = (lane >> 4) * 4;
    #pragma unroll
    for (int rr = 0; rr < 4; ++rr) {
        int item2 = blockIdx.x * 64 + wave * 16 + m0 + rr;
        int s2 = item2 / SEQ;
        int t2 = item2 - s2 * SEQ;
        float* dst = eout + ((size_t)t2 * BSEQ + s2) * KTAGS;
        dst[0 * 16 + col] = __expf(acc0[rr]);
        dst[1 * 16 + col] = __expf(acc1[rr]);
        dst[2 * 16 + col] = __expf(acc2[rr]);
        float v3 = (48 + col >= EOS_T) ? 1e-45f : __expf(acc3[rr]);
        dst[3 * 16 + col] = v3;
    }
}

// ---------------------------------------------------------------------------
// Kernel 2: forward recursion in matrix form, 16 sequences per 64-lane wave.
//   X_{t+1}(64x16) = (M^T . X_t) * E_t, as 4 C-tiles (16 tags x 16 seqs).
//   X is the MFMA B operand; seq stays at lane&15 in both B and C layouts, so
//   C -> next-B is a 4-lane-family regroup: permlane32_swap + permlane16_swap.
// Also computes the tagged (supervised) log-prob for its 16 sequences.
// ---------------------------------------------------------------------------
__global__ __launch_bounds__(64) void fwd_kernel(
    const float* __restrict__ WA, const int* __restrict__ tags,
    const float* __restrict__ eout, float* __restrict__ out)
{
    const int blk  = blockIdx.x;       // 0..31, seqs blk*16..+15
    const int lane = threadIdx.x;
    const int g    = lane >> 4;        // lane group 0..3
    const int c    = lane & 15;        // seq within block (B/C col); A row

    // ---- A-frags: Af[rb][h] = M^T[rb*16+row][h*32+k'] row=c, k'=g*8+j ----
    // M = exp(WA) with column BOS zeroed => M^T row 63 zero.
    bf16x8 Af[4][2];
    #pragma unroll
    for (int rb = 0; rb < 4; ++rb) {
        #pragma unroll
        for (int h = 0; h < 2; ++h) {
            short tmp[8];
            #pragma unroll
            for (int j = 0; j < 8; ++j) {
                float w = WA[(h * 32 + g * 8 + j) * KTAGS + rb * 16 + c];
                float v = (rb * 16 + c == BOS_T) ? 0.f : __expf(w);
                tmp[j] = f2bf(v);
            }
            Af[rb][h] = *(const bf16x8*)tmp;
        }
    }

    // ---- init X_0 = onehot(BOS=63) for every seq: nb1 elem j=7 on g==3 ----
    union { unsigned int u[4]; bf16x8 v; } qi0, qi1;
    qi0.u[0] = qi0.u[1] = qi0.u[2] = qi0.u[3] = 0u;
    qi1.u[0] = qi1.u[1] = qi1.u[2] = 0u;
    qi1.u[3] = (g == 3) ? 0x3F800000u : 0u;   // high16 = bf16(1.0)
    bf16x8 nb0 = qi0.v, nb1 = qi1.v;

    float logsum = 0.f;

    // e addressing: float addr = (t*512 + blk*16 + c)*64 + T*16 + g*4
    const float* ep0 = eout + ((size_t)(blk * 16 + c)) * KTAGS + g * 4;

#define LD4(tt, S0, S1, S2, S3)                                             \
    {                                                                       \
        const float* p_ = ep0 + (size_t)(tt) * (BSEQ * KTAGS);              \
        S0 = *(const float4*)(p_);                                          \
        S1 = *(const float4*)(p_ + 16);                                     \
        S2 = *(const float4*)(p_ + 32);                                     \
        S3 = *(const float4*)(p_ + 48);                                     \
    }

#define STEP(E0, E1, E2, E3, RESC)                                          \
    {                                                                       \
        f32x4 zz = {0.f, 0.f, 0.f, 0.f};                                    \
        f32x4 c0 = __builtin_amdgcn_mfma_f32_16x16x32_bf16(Af[0][0], nb0, zz, 0, 0, 0); \
        c0 = __builtin_amdgcn_mfma_f32_16x16x32_bf16(Af[0][1], nb1, c0, 0, 0, 0); \
        f32x4 c1 = __builtin_amdgcn_mfma_f32_16x16x32_bf16(Af[1][0], nb0, zz, 0, 0, 0); \
        c1 = __builtin_amdgcn_mfma_f32_16x16x32_bf16(Af[1][1], nb1, c1, 0, 0, 0); \
        f32x4 c2 = __builtin_amdgcn_mfma_f32_16x16x32_bf16(Af[2][0], nb0, zz, 0, 0, 0); \
        c2 = __builtin_amdgcn_mfma_f32_16x16x32_bf16(Af[2][1], nb1, c2, 0, 0, 0); \
        f32x4 c3 = __builtin_amdgcn_mfma_f32_16x16x32_bf16(Af[3][0], nb0, zz, 0, 0, 0); \
        c3 = __builtin_amdgcn_mfma_f32_16x16x32_bf16(Af[3][1], nb1, c3, 0, 0, 0); \
        float m00 = c0[0]*E0.x, m01 = c0[1]*E0.y, m02 = c0[2]*E0.z, m03 = c0[3]*E0.w; \
        float m10 = c1[0]*E1.x, m11 = c1[1]*E1.y, m12 = c1[2]*E1.z, m13 = c1[3]*E1.w; \
        float m20 = c2[0]*E2.x, m21 = c2[1]*E2.y, m22 = c2[2]*E2.z, m23 = c2[3]*E2.w; \
        float m30 = c3[0]*E3.x, m31 = c3[1]*E3.y, m32 = c3[2]*E3.z, m33 = c3[3]*E3.w; \
        if (RESC) {                                                         \
            float mx = fmaxf(fmaxf(fmaxf(m00, m01), fmaxf(m02, m03)),       \
                             fmaxf(fmaxf(m10, m11), fmaxf(m12, m13)));      \
            mx = fmaxf(mx, fmaxf(fmaxf(m20, m21), fmaxf(m22, m23)));        \
            mx = fmaxf(mx, fmaxf(fmaxf(m30, m31), fmaxf(m32, m33)));        \
            mx = fmaxf(mx, __shfl_xor(mx, 16));                             \
            mx = fmaxf(mx, __shfl_xor(mx, 32));                             \
            float rs = __builtin_amdgcn_rcpf(mx);                           \
            m00 *= rs; m01 *= rs; m02 *= rs; m03 *= rs;                     \
            m10 *= rs; m11 *= rs; m12 *= rs; m13 *= rs;                     \
            m20 *= rs; m21 *= rs; m22 *= rs; m23 *= rs;                     \
            m30 *= rs; m31 *= rs; m32 *= rs; m33 *= rs;                     \
            logsum += __logf(mx);                                           \
        }                                                                   \
        unsigned int p00, p01, p10, p11, p20, p21, p30, p31;                \
        asm("v_cvt_pk_bf16_f32 %0, %1, %2" : "=v"(p00) : "v"(m00), "v"(m01)); \
        asm("v_cvt_pk_bf16_f32 %0, %1, %2" : "=v"(p01) : "v"(m02), "v"(m03)); \
        asm("v_cvt_pk_bf16_f32 %0, %1, %2" : "=v"(p10) : "v"(m10), "v"(m11)); \
        asm("v_cvt_pk_bf16_f32 %0, %1, %2" : "=v"(p11) : "v"(m12), "v"(m13)); \
        asm("v_cvt_pk_bf16_f32 %0, %1, %2" : "=v"(p20) : "v"(m20), "v"(m21)); \
        asm("v_cvt_pk_bf16_f32 %0, %1, %2" : "=v"(p21) : "v"(m22), "v"(m23)); \
        asm("v_cvt_pk_bf16_f32 %0, %1, %2" : "=v"(p30) : "v"(m30), "v"(m31)); \
        asm("v_cvt_pk_bf16_f32 %0, %1, %2" : "=v"(p31) : "v"(m32), "v"(m33)); \
        unsigned int a0 = p00, b0 = p10;                                    \
        asm volatile("v_permlane32_swap_b32 %0, %1" : "+v"(a0), "+v"(b0));  \
        asm volatile("v_permlane16_swap_b32 %0, %1" : "+v"(a0), "+v"(b0));  \
        unsigned int a1 = p01, b1 = p11;                                    \
        asm volatile("v_permlane32_swap_b32 %0, %1" : "+v"(a1), "+v"(b1));  \
        asm volatile("v_permlane16_swap_b32 %0, %1" : "+v"(a1), "+v"(b1));  \
        unsigned int a2 = p20, b2 = p30;                                    \
        asm volatile("v_permlane32_swap_b32 %0, %1" : "+v"(a2), "+v"(b2));  \
        asm volatile("v_permlane16_swap_b32 %0, %1" : "+v"(a2), "+v"(b2));  \
        unsigned int a3 = p21, b3 = p31;                                    \
        asm volatile("v_permlane32_swap_b32 %0, %1" : "+v"(a3), "+v"(b3));  \
        asm volatile("v_permlane16_swap_b32 %0, %1" : "+v"(a3), "+v"(b3));  \
        union { unsigned int u[4]; bf16x8 v; } q0_, q1_;                    \
        q0_.u[0] = a0; q0_.u[1] = a1; q0_.u[2] = b0; q0_.u[3] = b1;         \
        q1_.u[0] = a2; q1_.u[1] = a3; q1_.u[2] = b2; q1_.u[3] = b3;         \
        nb0 = q0_.v; nb1 = q1_.v;                                           \
    }

    float4 sA0, sA1, sA2, sA3, sB0, sB1, sB2, sB3;
    float4 sC0, sC1, sC2, sC3, sD0, sD1, sD2, sD3;
    LD4(0, sA0, sA1, sA2, sA3);
    LD4(1, sB0, sB1, sB2, sB3);
    LD4(2, sC0, sC1, sC2, sC3);
    LD4(3, sD0, sD1, sD2, sD3);

    for (int t = 0; t < SEQ - 2; t += 4) {   // steps 0..123
        int p4 = t + 4, p5 = t + 5, p6 = t + 6, p7 = t + 7;
        if (p5 > SEQ - 1) p5 = SEQ - 1;
        if (p6 > SEQ - 1) p6 = SEQ - 1;
        if (p7 > SEQ - 1) p7 = SEQ - 1;
        STEP(sA0, sA1, sA2, sA3, false); LD4(p4, sA0, sA1, sA2, sA3);
        STEP(sB0, sB1, sB2, sB3, false); LD4(p5, sB0, sB1, sB2, sB3);
        STEP(sC0, sC1, sC2, sC3, false); LD4(p6, sC0, sC1, sC2, sC3);
        bool rsc = ((t & 15) == 12);
        STEP(sD0, sD1, sD2, sD3, rsc);   LD4(p7, sD0, sD1, sD2, sD3);
    }
    STEP(sA0, sA1, sA2, sA3, false);     // step 124
    STEP(sB0, sB1, sB2, sB3, false);     // step 125

    // ---- final transition into EOS: tile rb=3 row 14 (g==3, reg 2) ----
    f32x4 zz = {0.f, 0.f, 0.f, 0.f};
    f32x4 cF = __builtin_amdgcn_mfma_f32_16x16x32_bf16(Af[3][0], nb0, zz, 0, 0, 0);
    cF = __builtin_amdgcn_mfma_f32_16x16x32_bf16(Af[3][1], nb1, cF, 0, 0, 0);
    float unsup = __logf(cF[2]) + logsum;    // valid on lanes 48..63 (seq = c)

    // ---- tagged pass: 4 lanes per seq ----
    const int sl = lane >> 2;          // seq within block
    const int q  = lane & 3;
    const int* trs = tags + (size_t)(blk * 16 + sl) * TLEN;
    float tsum = 0.f;
    #pragma unroll 4
    for (int m = 0; m < 32; ++m) {
        int t = 1 + q + 4 * m;
        if (t <= SEQ) {
            int cur  = trs[t];
            int prev = (t == 1) ? BOS_T : trs[t - 1];
            tsum += WA[prev * KTAGS + cur]
                  + __logf(eout[((size_t)(t - 1) * BSEQ + blk * 16 + sl) * KTAGS + cur]);
        }
    }
    tsum += __shfl_xor(tsum, 1);
    tsum += __shfl_xor(tsum, 2);
    float tagged = tsum + WA[trs[SEQ] * KTAGS + EOS_T];   // valid on all 4 lanes of seq sl

    // route seq c's tagged value to lane 48+c and store
    float tg = __shfl(tagged, c * 4);
    if (lane >= 48) out[blk * 16 + c] = tg - unsup;

#undef LD4
#undef STEP
}

// ---------------------------------------------------------------------------
extern "C" void kernel_launch(void* const* d_in, const int* in_sizes, int n_in,
                              void* d_out, int out_size, void* d_ws, size_t ws_size,
                              hipStream_t stream) {
    const float* WA     = (const float*)d_in[0];
    const float* ThetaB = (const float*)d_in[1];
    const float* E      = (const float*)d_in[2];
    const int*   words  = (const int*)d_in[3];
    const int*   tags   = (const int*)d_in[4];
    float*       out    = (float*)d_out;

    float* eout = (float*)d_ws;                          // 16,515,072 B
    short* thp  = (short*)((char*)d_ws + 16515072);      // 65,536 B

    pack_theta_kernel<<<dim3(16), dim3(256), 0, stream>>>(ThetaB, thp);
    emit_kernel<<<dim3(NITEMS / 64), dim3(256), 0, stream>>>(E, words, thp, eout);
    fwd_kernel<<<dim3(BSEQ / 16), dim3(64), 0, stream>>>(WA, tags, eout, out);
}